// Round 7
// baseline (139.789 us; speedup 1.0000x reference)
//
#include <hip/hip_runtime.h>
#include <hip/hip_cooperative_groups.h>
#include <math.h>

#define B 1024
#define C 512
#define S 32
#define E 128

typedef __attribute__((ext_vector_type(8))) short bf16x8;
typedef __attribute__((ext_vector_type(4))) float f32x4;

// ---------------------------------------------------------------------------
// Workspace layout (float units):
//   xfrag  : bf16 [B/16][4 kt][64 lane][8 j]   @ f0        (65536 f)
//   wfrag  : bf16 [C][4 kt][2 mt][64][8]       @ f65536    (1048576 f)
//   gfrag  : bf16 [C][2 mt][64][8]             @ f1114112  (262144 f)
//   logits : f32 [B][C]                        @ f1376256  (524288 f)
//   loss   : f32 [B]                           @ f1900544
// Fragment mapping (mfma_f32_16x16x32_bf16 A/B operand):
//   frag[j] = M[row = lane&15][k = 4*(lane>>4) + (j&3) + 16*(j>>2)]
// D mapping: D[row = 4*(lane>>4)+r][col = lane&15]
// ---------------------------------------------------------------------------
#define OFF_XFRAG  0
#define OFF_WFRAG  65536
#define OFF_GFRAG  1114112
#define OFF_LOGITS 1376256
#define OFF_LOSS   1900544

namespace cg = cooperative_groups;

__device__ inline unsigned short f2bf(float f) {
    unsigned u = __float_as_uint(f);
    return (unsigned short)((u + 0x7fffu + ((u >> 16) & 1u)) >> 16);
}

// ===========================================================================
// Fused cooperative kernel (grid-size agnostic; grid must be multiple of 8)
// ===========================================================================
__global__ __launch_bounds__(256, 2) void k_fused(const float* __restrict__ x,
                                                  const float* __restrict__ W,
                                                  const float* __restrict__ y,
                                                  const float* __restrict__ s_ptr,
                                                  unsigned short* __restrict__ xfrag,
                                                  unsigned short* __restrict__ wfrag,
                                                  unsigned short* __restrict__ gfrag,
                                                  float* __restrict__ logits,
                                                  float* __restrict__ loss,
                                                  float* __restrict__ out) {
    __shared__ int4 lds4[2048];  // 32 KB, aliased per phase
    cg::grid_group grid = cg::this_grid();
    int t = threadIdx.x;
    int bid = blockIdx.x;
    int G = gridDim.x;
    int w = t >> 6, lane = t & 63;

    // ================= P1: prep (576 items: 64 x-tiles + 512 classes) =======
    {
        float (*sM)[132] = reinterpret_cast<float (*)[132]>(lds4);
        int4* wf = reinterpret_cast<int4*>(reinterpret_cast<char*>(lds4) + 16896);
        for (int wi = bid; wi < 576; wi += G) {
            if (wi < 64) {
                const float4* gx = reinterpret_cast<const float4*>(x + (size_t)wi * 16 * 128);
                #pragma unroll
                for (int i = 0; i < 2; ++i) {
                    int ci = t + 256 * i;
                    *reinterpret_cast<float4*>(&sM[ci >> 5][(ci & 31) << 2]) = gx[ci];
                }
                __syncthreads();
                int r = t >> 4, j = t & 15;
                float ss = 0.f;
                #pragma unroll
                for (int i = 0; i < 8; ++i) { float v = sM[r][j + 16 * i]; ss += v * v; }
                #pragma unroll
                for (int m = 1; m < 16; m <<= 1) ss += __shfl_xor(ss, m, 16);
                float sc = 1.0f / fmaxf(sqrtf(ss), 1e-12f);
                #pragma unroll
                for (int i = 0; i < 8; ++i) sM[r][j + 16 * i] *= sc;
                __syncthreads();
                int row = lane & 15, k0 = w * 32 + 4 * (lane >> 4);
                union { unsigned short u[8]; int4 v; } pk;
                #pragma unroll
                for (int g = 0; g < 2; ++g) {
                    float4 rv = *reinterpret_cast<const float4*>(&sM[row][k0 + 16 * g]);
                    pk.u[4 * g + 0] = f2bf(rv.x); pk.u[4 * g + 1] = f2bf(rv.y);
                    pk.u[4 * g + 2] = f2bf(rv.z); pk.u[4 * g + 3] = f2bf(rv.w);
                }
                reinterpret_cast<int4*>(xfrag)[(size_t)wi * 256 + t] = pk.v;
            } else {
                int c = wi - 64;
                const float4* gw = reinterpret_cast<const float4*>(W + (size_t)c * S * E);
                #pragma unroll
                for (int i = 0; i < 4; ++i) {
                    int ci = t + 256 * i;
                    *reinterpret_cast<float4*>(&sM[ci >> 5][(ci & 31) << 2]) = gw[ci];
                }
                __syncthreads();
                int r = t >> 3, j = t & 7;
                float ss = 0.f;
                #pragma unroll
                for (int i = 0; i < 16; ++i) { float v = sM[r][j + 8 * i]; ss += v * v; }
                #pragma unroll
                for (int m = 1; m < 8; m <<= 1) ss += __shfl_xor(ss, m, 8);
                float sc = 1.0f / fmaxf(sqrtf(ss), 1e-12f);
                #pragma unroll
                for (int i = 0; i < 16; ++i) sM[r][j + 8 * i] *= sc;
                __syncthreads();
                int4* gwf = reinterpret_cast<int4*>(wfrag) + (size_t)c * 512;
                #pragma unroll
                for (int ci = t; ci < 512; ci += 256) {
                    int kt = ci >> 7, mt = (ci >> 6) & 1, ln = ci & 63;
                    int srow = mt * 16 + (ln & 15), k0 = kt * 32 + 4 * (ln >> 4);
                    union { unsigned short u[8]; int4 v; } pk;
                    #pragma unroll
                    for (int g = 0; g < 2; ++g) {
                        float4 rv = *reinterpret_cast<const float4*>(&sM[srow][k0 + 16 * g]);
                        pk.u[4 * g + 0] = f2bf(rv.x); pk.u[4 * g + 1] = f2bf(rv.y);
                        pk.u[4 * g + 2] = f2bf(rv.z); pk.u[4 * g + 3] = f2bf(rv.w);
                    }
                    wf[ci] = pk.v;
                    gwf[ci] = pk.v;
                }
                __syncthreads();
                if (w < 2) {
                    const bf16x8* f = reinterpret_cast<const bf16x8*>(wf);
                    f32x4 d0 = {0.f, 0.f, 0.f, 0.f}, d1 = d0;
                    #pragma unroll
                    for (int kt = 0; kt < 4; ++kt) {
                        bf16x8 bnt = f[kt * 128 + w * 64 + lane];
                        bf16x8 a0  = f[kt * 128 + lane];
                        bf16x8 a1  = f[kt * 128 + 64 + lane];
                        d0 = __builtin_amdgcn_mfma_f32_16x16x32_bf16(a0, bnt, d0, 0, 0, 0);
                        d1 = __builtin_amdgcn_mfma_f32_16x16x32_bf16(a1, bnt, d1, 0, 0, 0);
                    }
                    union { unsigned short u[8]; int4 v; } pk;
                    #pragma unroll
                    for (int r2 = 0; r2 < 4; ++r2) {
                        pk.u[r2]     = f2bf(d0[r2]);
                        pk.u[r2 + 4] = f2bf(d1[r2]);
                    }
                    reinterpret_cast<int4*>(gfrag)[(size_t)c * 128 + w * 64 + lane] = pk.v;
                }
            }
            __syncthreads();
        }
    }
    grid.sync();

    // ================= P2: logits (1024 tiles; G%8==0 -> bx fixed per block) =
    {
        int4* sx = lds4;
        const bf16x8* fX = reinterpret_cast<const bf16x8*>(lds4);  // [bt][kt][64]
        for (int tile = bid; tile < 1024; tile += G) {
            int bx = tile & 7, cy = tile >> 3;
            int b0 = bx * 128;
            if (tile == bid) {  // bx invariant across iterations (G%8==0)
                const int4* gX = reinterpret_cast<const int4*>(xfrag) + (size_t)(b0 >> 4) * 256;
                #pragma unroll
                for (int i = 0; i < 8; ++i) sx[t + 256 * i] = gX[t + 256 * i];
            }
            __syncthreads();

            int c = cy * 4 + w;
            const int4* gW = reinterpret_cast<const int4*>(wfrag) + (size_t)c * 512;
            const int4* gG = reinterpret_cast<const int4*>(gfrag) + (size_t)c * 128;
            bf16x8 a[4][2];
            #pragma unroll
            for (int kt = 0; kt < 4; ++kt) {
                a[kt][0] = reinterpret_cast<const bf16x8*>(gW)[kt * 128 + lane];
                a[kt][1] = reinterpret_cast<const bf16x8*>(gW)[kt * 128 + 64 + lane];
            }
            bf16x8 g0 = reinterpret_cast<const bf16x8*>(gG)[lane];
            bf16x8 g1 = reinterpret_cast<const bf16x8*>(gG)[64 + lane];

            f32x4 acc[2][8];
            #pragma unroll
            for (int m = 0; m < 2; ++m)
                #pragma unroll
                for (int bt = 0; bt < 8; ++bt) acc[m][bt] = (f32x4){0.f, 0.f, 0.f, 0.f};

            #pragma unroll
            for (int kt = 0; kt < 4; ++kt) {
                #pragma unroll
                for (int bt = 0; bt < 8; ++bt) {
                    bf16x8 bv = fX[bt * 256 + kt * 64 + lane];
                    acc[0][bt] = __builtin_amdgcn_mfma_f32_16x16x32_bf16(a[kt][0], bv, acc[0][bt], 0, 0, 0);
                    acc[1][bt] = __builtin_amdgcn_mfma_f32_16x16x32_bf16(a[kt][1], bv, acc[1][bt], 0, 0, 0);
                }
            }

            #pragma unroll
            for (int bt = 0; bt < 8; ++bt) {
                union { unsigned short u[8]; bf16x8 v; } p;
                #pragma unroll
                for (int r = 0; r < 4; ++r) {
                    p.u[r]     = f2bf(acc[0][bt][r]);
                    p.u[r + 4] = f2bf(acc[1][bt][r]);
                }
                f32x4 h0 = {0.f, 0.f, 0.f, 0.f}, h1 = h0;
                h0 = __builtin_amdgcn_mfma_f32_16x16x32_bf16(g0, p.v, h0, 0, 0, 0);
                h1 = __builtin_amdgcn_mfma_f32_16x16x32_bf16(g1, p.v, h1, 0, 0, 0);
                float n = 0.f, q = 0.f;
                #pragma unroll
                for (int r = 0; r < 4; ++r) {
                    n += acc[0][bt][r] * acc[0][bt][r] + acc[1][bt][r] * acc[1][bt][r];
                    q += acc[0][bt][r] * h0[r] + acc[1][bt][r] * h1[r];
                }
                n += __shfl_xor(n, 16); n += __shfl_xor(n, 32);
                q += __shfl_xor(q, 16); q += __shfl_xor(q, 32);
                if (lane < 16)
                    logits[(size_t)(b0 + bt * 16 + lane) * C + c] = n / fmaxf(sqrtf(q), 1e-12f);
            }
        }
    }
    grid.sync();

    // ================= P3: loss per row (stride loop, one wave per row) =====
    {
        float s = s_ptr[0];
        for (int r4 = bid; r4 < 256; r4 += G) {
            int row = r4 * 4 + w;
            const float4* lr = reinterpret_cast<const float4*>(logits + (size_t)row * C);
            const float4* yr = reinterpret_cast<const float4*>(y + (size_t)row * C);
            float4 l0 = lr[lane * 2], l1 = lr[lane * 2 + 1];
            float4 y0 = yr[lane * 2], y1 = yr[lane * 2 + 1];
            float z[8] = {l0.x * s, l0.y * s, l0.z * s, l0.w * s,
                          l1.x * s, l1.y * s, l1.z * s, l1.w * s};
            float yv[8] = {y0.x, y0.y, y0.z, y0.w, y1.x, y1.y, y1.z, y1.w};
            float m = z[0];
            #pragma unroll
            for (int i = 1; i < 8; ++i) m = fmaxf(m, z[i]);
            #pragma unroll
            for (int off = 1; off < 64; off <<= 1) m = fmaxf(m, __shfl_xor(m, off));
            float se = 0.f, yz = 0.f;
            #pragma unroll
            for (int i = 0; i < 8; ++i) { se += expf(z[i] - m); yz += yv[i] * z[i]; }
            #pragma unroll
            for (int off = 1; off < 64; off <<= 1) {
                se += __shfl_xor(se, off);
                yz += __shfl_xor(yz, off);
            }
            if (lane == 0) loss[row] = m + logf(se) - yz;
        }
    }
    grid.sync();

    // ================= P4: final reduce (block 0) ===========================
    if (bid == 0) {
        float* rr = reinterpret_cast<float*>(lds4);
        float v = loss[t] + loss[t + 256] + loss[t + 512] + loss[t + 768];
        #pragma unroll
        for (int off = 32; off; off >>= 1) v += __shfl_xor(v, off);
        if ((t & 63) == 0) rr[w] = v;
        __syncthreads();
        if (t == 0) out[0] = (rr[0] + rr[1] + rr[2] + rr[3]) * (1.0f / (float)B);
    }
}

// ===========================================================================
// Fallback pipeline (round-5 proven kernels)
// ===========================================================================
__global__ __launch_bounds__(256) void k_prep(const float* __restrict__ x,
                                              const float* __restrict__ W,
                                              unsigned short* __restrict__ xfrag,
                                              unsigned short* __restrict__ wfrag,
                                              unsigned short* __restrict__ gfrag) {
    __shared__ float sM[32][132];
    __shared__ int4 wf[512];
    int t = threadIdx.x;
    int blk = blockIdx.x;
    if (blk < 64) {
        const float4* gx = reinterpret_cast<const float4*>(x + (size_t)blk * 16 * 128);
        #pragma unroll
        for (int i = 0; i < 2; ++i) {
            int ci = t + 256 * i;
            *reinterpret_cast<float4*>(&sM[ci >> 5][(ci & 31) << 2]) = gx[ci];
        }
        __syncthreads();
        int r = t >> 4, j = t & 15;
        float ss = 0.f;
        #pragma unroll
        for (int i = 0; i < 8; ++i) { float v = sM[r][j + 16 * i]; ss += v * v; }
        #pragma unroll
        for (int m = 1; m < 16; m <<= 1) ss += __shfl_xor(ss, m, 16);
        float sc = 1.0f / fmaxf(sqrtf(ss), 1e-12f);
        #pragma unroll
        for (int i = 0; i < 8; ++i) sM[r][j + 16 * i] *= sc;
        __syncthreads();
        int kt = t >> 6, lane = t & 63;
        int row = lane & 15, k0 = kt * 32 + 4 * (lane >> 4);
        union { unsigned short u[8]; int4 v; } pk;
        #pragma unroll
        for (int g = 0; g < 2; ++g) {
            float4 rv = *reinterpret_cast<const float4*>(&sM[row][k0 + 16 * g]);
            pk.u[4 * g + 0] = f2bf(rv.x); pk.u[4 * g + 1] = f2bf(rv.y);
            pk.u[4 * g + 2] = f2bf(rv.z); pk.u[4 * g + 3] = f2bf(rv.w);
        }
        reinterpret_cast<int4*>(xfrag)[(size_t)blk * 256 + t] = pk.v;
    } else {
        int c = blk - 64;
        const float4* gw = reinterpret_cast<const float4*>(W + (size_t)c * S * E);
        #pragma unroll
        for (int i = 0; i < 4; ++i) {
            int ci = t + 256 * i;
            *reinterpret_cast<float4*>(&sM[ci >> 5][(ci & 31) << 2]) = gw[ci];
        }
        __syncthreads();
        int r = t >> 3, j = t & 7;
        float ss = 0.f;
        #pragma unroll
        for (int i = 0; i < 16; ++i) { float v = sM[r][j + 8 * i]; ss += v * v; }
        #pragma unroll
        for (int m = 1; m < 8; m <<= 1) ss += __shfl_xor(ss, m, 8);
        float sc = 1.0f / fmaxf(sqrtf(ss), 1e-12f);
        #pragma unroll
        for (int i = 0; i < 16; ++i) sM[r][j + 8 * i] *= sc;
        __syncthreads();
        int4* gwf = reinterpret_cast<int4*>(wfrag) + (size_t)c * 512;
        #pragma unroll
        for (int ci = t; ci < 512; ci += 256) {
            int kt = ci >> 7, mt = (ci >> 6) & 1, ln = ci & 63;
            int srow = mt * 16 + (ln & 15), k0 = kt * 32 + 4 * (ln >> 4);
            union { unsigned short u[8]; int4 v; } pk;
            #pragma unroll
            for (int g = 0; g < 2; ++g) {
                float4 rv = *reinterpret_cast<const float4*>(&sM[srow][k0 + 16 * g]);
                pk.u[4 * g + 0] = f2bf(rv.x); pk.u[4 * g + 1] = f2bf(rv.y);
                pk.u[4 * g + 2] = f2bf(rv.z); pk.u[4 * g + 3] = f2bf(rv.w);
            }
            wf[ci] = pk.v;
            gwf[ci] = pk.v;
        }
        __syncthreads();
        int w = t >> 6, lane = t & 63;
        if (w < 2) {
            const bf16x8* f = reinterpret_cast<const bf16x8*>(wf);
            f32x4 d0 = {0.f, 0.f, 0.f, 0.f}, d1 = d0;
            #pragma unroll
            for (int kt = 0; kt < 4; ++kt) {
                bf16x8 bnt = f[kt * 128 + w * 64 + lane];
                bf16x8 a0  = f[kt * 128 + lane];
                bf16x8 a1  = f[kt * 128 + 64 + lane];
                d0 = __builtin_amdgcn_mfma_f32_16x16x32_bf16(a0, bnt, d0, 0, 0, 0);
                d1 = __builtin_amdgcn_mfma_f32_16x16x32_bf16(a1, bnt, d1, 0, 0, 0);
            }
            union { unsigned short u[8]; int4 v; } pk;
            #pragma unroll
            for (int r2 = 0; r2 < 4; ++r2) {
                pk.u[r2]     = f2bf(d0[r2]);
                pk.u[r2 + 4] = f2bf(d1[r2]);
            }
            reinterpret_cast<int4*>(gfrag)[(size_t)c * 128 + w * 64 + lane] = pk.v;
        }
    }
}

__global__ __launch_bounds__(256) void k_logits_mfma(const unsigned short* __restrict__ xfrag,
                                                     const unsigned short* __restrict__ wfrag,
                                                     const unsigned short* __restrict__ gfrag,
                                                     float* __restrict__ logits) {
    __shared__ int4 smem[2048];
    int t = threadIdx.x;
    int w = t >> 6, lane = t & 63;
    int b0 = blockIdx.x * 128;
    int c = blockIdx.y * 4 + w;

    const int4* gW = reinterpret_cast<const int4*>(wfrag) + (size_t)c * 512;
    const int4* gG = reinterpret_cast<const int4*>(gfrag) + (size_t)c * 128;
    bf16x8 a[4][2];
    #pragma unroll
    for (int kt = 0; kt < 4; ++kt) {
        a[kt][0] = reinterpret_cast<const bf16x8*>(gW)[kt * 128 + lane];
        a[kt][1] = reinterpret_cast<const bf16x8*>(gW)[kt * 128 + 64 + lane];
    }
    bf16x8 g0 = reinterpret_cast<const bf16x8*>(gG)[lane];
    bf16x8 g1 = reinterpret_cast<const bf16x8*>(gG)[64 + lane];

    const int4* gX = reinterpret_cast<const int4*>(xfrag) + (size_t)(b0 >> 4) * 256;
    #pragma unroll
    for (int i = 0; i < 8; ++i) smem[t + 256 * i] = gX[t + 256 * i];
    __syncthreads();

    const bf16x8* fX = reinterpret_cast<const bf16x8*>(smem);

    f32x4 acc[2][8];
    #pragma unroll
    for (int m = 0; m < 2; ++m)
        #pragma unroll
        for (int bt = 0; bt < 8; ++bt) acc[m][bt] = (f32x4){0.f, 0.f, 0.f, 0.f};

    #pragma unroll
    for (int kt = 0; kt < 4; ++kt) {
        #pragma unroll
        for (int bt = 0; bt < 8; ++bt) {
            bf16x8 bv = fX[bt * 256 + kt * 64 + lane];
            acc[0][bt] = __builtin_amdgcn_mfma_f32_16x16x32_bf16(a[kt][0], bv, acc[0][bt], 0, 0, 0);
            acc[1][bt] = __builtin_amdgcn_mfma_f32_16x16x32_bf16(a[kt][1], bv, acc[1][bt], 0, 0, 0);
        }
    }

    #pragma unroll
    for (int bt = 0; bt < 8; ++bt) {
        union { unsigned short u[8]; bf16x8 v; } p;
        #pragma unroll
        for (int r = 0; r < 4; ++r) {
            p.u[r]     = f2bf(acc[0][bt][r]);
            p.u[r + 4] = f2bf(acc[1][bt][r]);
        }
        f32x4 h0 = {0.f, 0.f, 0.f, 0.f}, h1 = h0;
        h0 = __builtin_amdgcn_mfma_f32_16x16x32_bf16(g0, p.v, h0, 0, 0, 0);
        h1 = __builtin_amdgcn_mfma_f32_16x16x32_bf16(g1, p.v, h1, 0, 0, 0);
        float n = 0.f, q = 0.f;
        #pragma unroll
        for (int r = 0; r < 4; ++r) {
            n += acc[0][bt][r] * acc[0][bt][r] + acc[1][bt][r] * acc[1][bt][r];
            q += acc[0][bt][r] * h0[r] + acc[1][bt][r] * h1[r];
        }
        n += __shfl_xor(n, 16); n += __shfl_xor(n, 32);
        q += __shfl_xor(q, 16); q += __shfl_xor(q, 32);
        if (lane < 16)
            logits[(size_t)(b0 + bt * 16 + lane) * C + c] = n / fmaxf(sqrtf(q), 1e-12f);
    }
}

__global__ __launch_bounds__(256) void k_loss(const float* __restrict__ logits,
                                              const float* __restrict__ y,
                                              const float* __restrict__ s_ptr,
                                              float* __restrict__ loss) {
    int row = blockIdx.x * 4 + (threadIdx.x >> 6);
    int lane = threadIdx.x & 63;
    float s = s_ptr[0];
    const float4* lr = reinterpret_cast<const float4*>(logits + (size_t)row * C);
    const float4* yr = reinterpret_cast<const float4*>(y + (size_t)row * C);
    float4 l0 = lr[lane * 2], l1 = lr[lane * 2 + 1];
    float4 y0 = yr[lane * 2], y1 = yr[lane * 2 + 1];
    float z[8] = {l0.x * s, l0.y * s, l0.z * s, l0.w * s,
                  l1.x * s, l1.y * s, l1.z * s, l1.w * s};
    float yv[8] = {y0.x, y0.y, y0.z, y0.w, y1.x, y1.y, y1.z, y1.w};
    float m = z[0];
    #pragma unroll
    for (int i = 1; i < 8; ++i) m = fmaxf(m, z[i]);
    #pragma unroll
    for (int off = 1; off < 64; off <<= 1) m = fmaxf(m, __shfl_xor(m, off));
    float se = 0.f, yz = 0.f;
    #pragma unroll
    for (int i = 0; i < 8; ++i) { se += expf(z[i] - m); yz += yv[i] * z[i]; }
    #pragma unroll
    for (int off = 1; off < 64; off <<= 1) {
        se += __shfl_xor(se, off);
        yz += __shfl_xor(yz, off);
    }
    if (lane == 0) loss[row] = m + logf(se) - yz;
}

__global__ void k_reduce(const float* __restrict__ loss, float* __restrict__ out) {
    int t = threadIdx.x;
    float v = loss[t] + loss[t + 256] + loss[t + 512] + loss[t + 768];
    #pragma unroll
    for (int off = 32; off; off >>= 1) v += __shfl_xor(v, off);
    __shared__ float r[4];
    if ((t & 63) == 0) r[t >> 6] = v;
    __syncthreads();
    if (t == 0) out[0] = (r[0] + r[1] + r[2] + r[3]) * (1.0f / (float)B);
}

extern "C" void kernel_launch(void* const* d_in, const int* in_sizes, int n_in,
                              void* d_out, int out_size, void* d_ws, size_t ws_size,
                              hipStream_t stream) {
    const float* x = (const float*)d_in[0];
    const float* y = (const float*)d_in[1];
    const float* W = (const float*)d_in[2];
    const float* s = (const float*)d_in[3];
    float* ws = (float*)d_ws;
    float* out = (float*)d_out;

    unsigned short* xfrag = (unsigned short*)(ws + OFF_XFRAG);
    unsigned short* wfrag = (unsigned short*)(ws + OFF_WFRAG);
    unsigned short* gfrag = (unsigned short*)(ws + OFF_GFRAG);
    float* logits = ws + OFF_LOGITS;
    float* loss   = ws + OFF_LOSS;

    // Try cooperative fused path with runtime-validated grid size.
    bool done = false;
    int nb = 0;
    hipError_t qe = hipOccupancyMaxActiveBlocksPerMultiprocessor(
        &nb, reinterpret_cast<const void*>(k_fused), 256, 0);
    if (qe == hipSuccess && nb > 0) {
        int G = nb * 256;
        if (G > 512) G = 512;
        G &= ~7;  // multiple of 8 (P2 X-tile invariance)
        if (G >= 8) {
            void* args[] = {(void*)&x, (void*)&W, (void*)&y, (void*)&s,
                            (void*)&xfrag, (void*)&wfrag, (void*)&gfrag,
                            (void*)&logits, (void*)&loss, (void*)&out};
            hipError_t le = hipLaunchCooperativeKernel(
                reinterpret_cast<void*>(k_fused), dim3(G), dim3(256), args, 0, stream);
            done = (le == hipSuccess);
        }
    }
    if (!done) {
        k_prep<<<576, 256, 0, stream>>>(x, W, xfrag, wfrag, gfrag);
        k_logits_mfma<<<dim3(B / 128, C / 4), 256, 0, stream>>>(xfrag, wfrag, gfrag, logits);
        k_loss<<<B / 4, 256, 0, stream>>>(logits, y, s, loss);
        k_reduce<<<1, 256, 0, stream>>>(loss, out);
    }
}

// Round 8
// 27.096 us; speedup vs baseline: 5.1590x; 5.1590x over previous
//
#include <hip/hip_runtime.h>
#include <math.h>

#define B 1024
#define C 512
#define S 32
#define E 128

typedef __attribute__((ext_vector_type(8))) short bf16x8;
typedef __attribute__((ext_vector_type(4))) float f32x4;

// ---------------------------------------------------------------------------
// Workspace layout (float units):
//   xfrag  : bf16 [B/16][4 kt][64 lane][8 j]   @ f0        (65536 f)
//   wfrag  : bf16 [C][4 kt][2 mt][64][8]       @ f65536    (1048576 f)
//   gfrag  : bf16 [C][2 mt][64][8]             @ f1114112  (262144 f)
//   logits : f32 [B][C]                        @ f1376256  (524288 f)
//   loss   : f32 [B]                           @ f1900544
// Fragment mapping (mfma_f32_16x16x32_bf16 A/B operand):
//   frag[j] = M[row = lane&15][k = 4*(lane>>4) + (j&3) + 16*(j>>2)]
// D mapping: D[row = 4*(lane>>4)+r][col = lane&15]
// ---------------------------------------------------------------------------
#define OFF_XFRAG  0
#define OFF_WFRAG  65536
#define OFF_GFRAG  1114112
#define OFF_LOGITS 1376256
#define OFF_LOSS   1900544

__device__ inline unsigned short f2bf(float f) {
    unsigned u = __float_as_uint(f);
    return (unsigned short)((u + 0x7fffu + ((u >> 16) & 1u)) >> 16);
}

// Fused prep: blocks [0,64) = x tiles (16 rows each); blocks [64,576) = one class.
__global__ __launch_bounds__(256) void k_prep(const float* __restrict__ x,
                                              const float* __restrict__ W,
                                              unsigned short* __restrict__ xfrag,
                                              unsigned short* __restrict__ wfrag,
                                              unsigned short* __restrict__ gfrag) {
    __shared__ float sM[32][132];
    __shared__ int4 wf[512];
    int t = threadIdx.x;
    int blk = blockIdx.x;
    if (blk < 64) {
        const float4* gx = reinterpret_cast<const float4*>(x + (size_t)blk * 16 * 128);
        #pragma unroll
        for (int i = 0; i < 2; ++i) {
            int ci = t + 256 * i;
            *reinterpret_cast<float4*>(&sM[ci >> 5][(ci & 31) << 2]) = gx[ci];
        }
        __syncthreads();
        int r = t >> 4, j = t & 15;
        float ss = 0.f;
        #pragma unroll
        for (int i = 0; i < 8; ++i) { float v = sM[r][j + 16 * i]; ss += v * v; }
        #pragma unroll
        for (int m = 1; m < 16; m <<= 1) ss += __shfl_xor(ss, m, 16);
        float sc = 1.0f / fmaxf(sqrtf(ss), 1e-12f);
        #pragma unroll
        for (int i = 0; i < 8; ++i) sM[r][j + 16 * i] *= sc;
        __syncthreads();
        int kt = t >> 6, lane = t & 63;
        int row = lane & 15, k0 = kt * 32 + 4 * (lane >> 4);
        union { unsigned short u[8]; int4 v; } pk;
        #pragma unroll
        for (int g = 0; g < 2; ++g) {
            float4 rv = *reinterpret_cast<const float4*>(&sM[row][k0 + 16 * g]);
            pk.u[4 * g + 0] = f2bf(rv.x); pk.u[4 * g + 1] = f2bf(rv.y);
            pk.u[4 * g + 2] = f2bf(rv.z); pk.u[4 * g + 3] = f2bf(rv.w);
        }
        reinterpret_cast<int4*>(xfrag)[(size_t)blk * 256 + t] = pk.v;
    } else {
        int c = blk - 64;
        const float4* gw = reinterpret_cast<const float4*>(W + (size_t)c * S * E);
        #pragma unroll
        for (int i = 0; i < 4; ++i) {
            int ci = t + 256 * i;
            *reinterpret_cast<float4*>(&sM[ci >> 5][(ci & 31) << 2]) = gw[ci];
        }
        __syncthreads();
        int r = t >> 3, j = t & 7;
        float ss = 0.f;
        #pragma unroll
        for (int i = 0; i < 16; ++i) { float v = sM[r][j + 8 * i]; ss += v * v; }
        #pragma unroll
        for (int m = 1; m < 8; m <<= 1) ss += __shfl_xor(ss, m, 8);
        float sc = 1.0f / fmaxf(sqrtf(ss), 1e-12f);
        #pragma unroll
        for (int i = 0; i < 16; ++i) sM[r][j + 8 * i] *= sc;
        __syncthreads();
        int4* gwf = reinterpret_cast<int4*>(wfrag) + (size_t)c * 512;
        #pragma unroll
        for (int ci = t; ci < 512; ci += 256) {
            int kt = ci >> 7, mt = (ci >> 6) & 1, ln = ci & 63;
            int srow = mt * 16 + (ln & 15), k0 = kt * 32 + 4 * (ln >> 4);
            union { unsigned short u[8]; int4 v; } pk;
            #pragma unroll
            for (int g = 0; g < 2; ++g) {
                float4 rv = *reinterpret_cast<const float4*>(&sM[srow][k0 + 16 * g]);
                pk.u[4 * g + 0] = f2bf(rv.x); pk.u[4 * g + 1] = f2bf(rv.y);
                pk.u[4 * g + 2] = f2bf(rv.z); pk.u[4 * g + 3] = f2bf(rv.w);
            }
            wf[ci] = pk.v;
            gwf[ci] = pk.v;
        }
        __syncthreads();
        int w = t >> 6, lane = t & 63;
        if (w < 2) {
            const bf16x8* f = reinterpret_cast<const bf16x8*>(wf);
            f32x4 d0 = {0.f, 0.f, 0.f, 0.f}, d1 = d0;
            #pragma unroll
            for (int kt = 0; kt < 4; ++kt) {
                bf16x8 bnt = f[kt * 128 + w * 64 + lane];
                bf16x8 a0  = f[kt * 128 + lane];
                bf16x8 a1  = f[kt * 128 + 64 + lane];
                d0 = __builtin_amdgcn_mfma_f32_16x16x32_bf16(a0, bnt, d0, 0, 0, 0);
                d1 = __builtin_amdgcn_mfma_f32_16x16x32_bf16(a1, bnt, d1, 0, 0, 0);
            }
            union { unsigned short u[8]; int4 v; } pk;
            #pragma unroll
            for (int r2 = 0; r2 < 4; ++r2) {
                pk.u[r2]     = f2bf(d0[r2]);
                pk.u[r2 + 4] = f2bf(d1[r2]);
            }
            reinterpret_cast<int4*>(gfrag)[(size_t)c * 128 + w * 64 + lane] = pk.v;
        }
    }
}

// Fused logits: block = 64 b-rows x 4 classes (wave w = class c0+w).
// 16KB LDS (X tile), acc[2][4], VGPR capped at 128 -> 4 blocks/CU for
// latency hiding (round-7 diagnosis: k_logits was latency-bound at ~2-3
// blocks/CU with long per-wave serial chains).
__global__ __launch_bounds__(256, 4) void k_logits_mfma(const unsigned short* __restrict__ xfrag,
                                                        const unsigned short* __restrict__ wfrag,
                                                        const unsigned short* __restrict__ gfrag,
                                                        float* __restrict__ logits) {
    __shared__ int4 smem[1024];  // 16KB: X tile (64 rows)
    int t = threadIdx.x;
    int w = t >> 6, lane = t & 63;
    int b0 = blockIdx.x * 64;
    int c = blockIdx.y * 4 + w;

    const int4* gW = reinterpret_cast<const int4*>(wfrag) + (size_t)c * 512;
    const int4* gG = reinterpret_cast<const int4*>(gfrag) + (size_t)c * 128;
    bf16x8 a[4][2];
    #pragma unroll
    for (int kt = 0; kt < 4; ++kt) {
        a[kt][0] = reinterpret_cast<const bf16x8*>(gW)[kt * 128 + lane];
        a[kt][1] = reinterpret_cast<const bf16x8*>(gW)[kt * 128 + 64 + lane];
    }

    const int4* gX = reinterpret_cast<const int4*>(xfrag) + (size_t)(b0 >> 4) * 256;
    #pragma unroll
    for (int i = 0; i < 4; ++i) smem[t + 256 * i] = gX[t + 256 * i];
    __syncthreads();

    const bf16x8* fX = reinterpret_cast<const bf16x8*>(smem);  // [bt][kt][64]

    f32x4 acc[2][4];
    #pragma unroll
    for (int m = 0; m < 2; ++m)
        #pragma unroll
        for (int bt = 0; bt < 4; ++bt) acc[m][bt] = (f32x4){0.f, 0.f, 0.f, 0.f};

    #pragma unroll
    for (int kt = 0; kt < 4; ++kt) {
        #pragma unroll
        for (int bt = 0; bt < 4; ++bt) {
            bf16x8 bv = fX[bt * 256 + kt * 64 + lane];
            acc[0][bt] = __builtin_amdgcn_mfma_f32_16x16x32_bf16(a[kt][0], bv, acc[0][bt], 0, 0, 0);
            acc[1][bt] = __builtin_amdgcn_mfma_f32_16x16x32_bf16(a[kt][1], bv, acc[1][bt], 0, 0, 0);
        }
    }

    bf16x8 g0 = reinterpret_cast<const bf16x8*>(gG)[lane];
    bf16x8 g1 = reinterpret_cast<const bf16x8*>(gG)[64 + lane];

    #pragma unroll
    for (int bt = 0; bt < 4; ++bt) {
        union { unsigned short u[8]; bf16x8 v; } p;
        #pragma unroll
        for (int r = 0; r < 4; ++r) {
            p.u[r]     = f2bf(acc[0][bt][r]);
            p.u[r + 4] = f2bf(acc[1][bt][r]);
        }
        f32x4 h0 = {0.f, 0.f, 0.f, 0.f}, h1 = h0;
        h0 = __builtin_amdgcn_mfma_f32_16x16x32_bf16(g0, p.v, h0, 0, 0, 0);
        h1 = __builtin_amdgcn_mfma_f32_16x16x32_bf16(g1, p.v, h1, 0, 0, 0);
        float n = 0.f, q = 0.f;
        #pragma unroll
        for (int r = 0; r < 4; ++r) {
            n += acc[0][bt][r] * acc[0][bt][r] + acc[1][bt][r] * acc[1][bt][r];
            q += acc[0][bt][r] * h0[r] + acc[1][bt][r] * h1[r];
        }
        n += __shfl_xor(n, 16); n += __shfl_xor(n, 32);
        q += __shfl_xor(q, 16); q += __shfl_xor(q, 32);
        if (lane < 16)
            logits[(size_t)(b0 + bt * 16 + lane) * C + c] = n / fmaxf(sqrtf(q), 1e-12f);
    }
}

// Loss per row (one wave per row, 4 rows per block) -> loss[b]. No atomics.
__global__ __launch_bounds__(256) void k_loss(const float* __restrict__ logits,
                                              const float* __restrict__ y,
                                              const float* __restrict__ s_ptr,
                                              float* __restrict__ loss) {
    int row = blockIdx.x * 4 + (threadIdx.x >> 6);
    int lane = threadIdx.x & 63;
    float s = s_ptr[0];
    const float4* lr = reinterpret_cast<const float4*>(logits + (size_t)row * C);
    const float4* yr = reinterpret_cast<const float4*>(y + (size_t)row * C);
    float4 l0 = lr[lane * 2], l1 = lr[lane * 2 + 1];
    float4 y0 = yr[lane * 2], y1 = yr[lane * 2 + 1];
    float z[8] = {l0.x * s, l0.y * s, l0.z * s, l0.w * s,
                  l1.x * s, l1.y * s, l1.z * s, l1.w * s};
    float yv[8] = {y0.x, y0.y, y0.z, y0.w, y1.x, y1.y, y1.z, y1.w};
    float m = z[0];
    #pragma unroll
    for (int i = 1; i < 8; ++i) m = fmaxf(m, z[i]);
    #pragma unroll
    for (int off = 1; off < 64; off <<= 1) m = fmaxf(m, __shfl_xor(m, off));
    float se = 0.f, yz = 0.f;
    #pragma unroll
    for (int i = 0; i < 8; ++i) { se += expf(z[i] - m); yz += yv[i] * z[i]; }
    #pragma unroll
    for (int off = 1; off < 64; off <<= 1) {
        se += __shfl_xor(se, off);
        yz += __shfl_xor(yz, off);
    }
    if (lane == 0) loss[row] = m + logf(se) - yz;
}

__global__ void k_reduce(const float* __restrict__ loss, float* __restrict__ out) {
    int t = threadIdx.x;
    float v = loss[t] + loss[t + 256] + loss[t + 512] + loss[t + 768];
    #pragma unroll
    for (int off = 32; off; off >>= 1) v += __shfl_xor(v, off);
    __shared__ float r[4];
    if ((t & 63) == 0) r[t >> 6] = v;
    __syncthreads();
    if (t == 0) out[0] = (r[0] + r[1] + r[2] + r[3]) * (1.0f / (float)B);
}

extern "C" void kernel_launch(void* const* d_in, const int* in_sizes, int n_in,
                              void* d_out, int out_size, void* d_ws, size_t ws_size,
                              hipStream_t stream) {
    const float* x = (const float*)d_in[0];
    const float* y = (const float*)d_in[1];
    const float* W = (const float*)d_in[2];
    const float* s = (const float*)d_in[3];
    float* ws = (float*)d_ws;
    float* out = (float*)d_out;

    unsigned short* xfrag = (unsigned short*)(ws + OFF_XFRAG);
    unsigned short* wfrag = (unsigned short*)(ws + OFF_WFRAG);
    unsigned short* gfrag = (unsigned short*)(ws + OFF_GFRAG);
    float* logits = ws + OFF_LOGITS;
    float* loss   = ws + OFF_LOSS;

    k_prep<<<576, 256, 0, stream>>>(x, W, xfrag, wfrag, gfrag);
    k_logits_mfma<<<dim3(B / 64, C / 4), 256, 0, stream>>>(xfrag, wfrag, gfrag, logits);
    k_loss<<<B / 4, 256, 0, stream>>>(logits, y, s, loss);
    k_reduce<<<1, 256, 0, stream>>>(loss, out);
}